// Round 1
// baseline (109401.038 us; speedup 1.0000x reference)
//
#include <hip/hip_runtime.h>
#include <stdint.h>

// Problem dims (fixed by the reference)
#define BSZ   1024
#define TT    8
#define DD    512
#define HH    512
#define NSEQ  (BSZ*TT)          // 8192 sequential steps per direction
#define FOURH (4*HH)            // 2048
#define POISON 0xAAAAAAAAu
#define G_ELEMS  ((size_t)2*NSEQ*FOURH)      // 33,554,432 floats (128 MB)
#define HB_ELEMS ((size_t)2*(NSEQ+1)*HH)     //  8,389,632 floats (32 MB)
#define POLL_CAP (1<<16)

// ---------------------------------------------------------------------------
// Init: poison the h-pipeline buffer, seed slot 0 with h0 (LSB-flip if it
// happens to equal the poison bit pattern).
// ---------------------------------------------------------------------------
__global__ void init_hbuf_k(float* __restrict__ hbuf, const float* __restrict__ h0)
{
  size_t idx = (size_t)blockIdx.x*blockDim.x + threadIdx.x;
  if (idx >= HB_ELEMS) return;
  int j = (int)(idx % HH);
  size_t r = idx / HH;
  int t   = (int)(r % (NSEQ+1));
  int dir = (int)(r / (NSEQ+1));
  uint32_t v;
  if (t == 0){
    uint32_t u = __float_as_uint(h0[dir*HH + j]);
    if (u == POISON) u ^= 1u;
    v = u;
  } else {
    v = POISON;
  }
  ((uint32_t*)hbuf)[idx] = v;
}

// ---------------------------------------------------------------------------
// Input-side GEMM: g[dir][n][m] = x[row]·W_ih_dir[m] + b_dir[m]
//   dir 0: row = n ; dir 1: row = n^7  (per-sample time reversal, T=8)
// fp32 LDS-tiled, 64x64 tile, 4x4 microtile, k-major LDS (float4 reads).
// ---------------------------------------------------------------------------
__global__ __launch_bounds__(256) void gemm_ih_k(
    const float* __restrict__ x,
    const float* __restrict__ Wf, const float* __restrict__ bf,
    const float* __restrict__ Wb, const float* __restrict__ bb,
    float* __restrict__ g)
{
  const int bm = blockIdx.x;          // 128 row tiles
  const int bn = blockIdx.y;          // 64 col tiles over combined N=4096
  const int n0  = bm*64;
  const int m0g = bn*64;
  const int dir = m0g >> 11;          // /2048
  const int m0  = m0g & 2047;
  const float* __restrict__ W    = dir ? Wb : Wf;
  const float* __restrict__ bias = dir ? bb : bf;

  __shared__ float As[32][68];        // [k][row], pad 68 keeps 16B align + banks spread
  __shared__ float Bs[32][68];

  const int tid = threadIdx.x;
  const int tx = tid & 15, ty = tid >> 4;
  float acc[4][4] = {};

  const int lr = tid >> 2;            // 0..63
  const int lk = (tid & 3) * 8;       // 0,8,16,24
  int arow = n0 + lr; if (dir) arow ^= 7;
  const float* ap = &x[(size_t)arow*DD];
  const float* wp = &W[(size_t)(m0+lr)*DD];

  for (int k0 = 0; k0 < DD; k0 += 32){
    float4 a0 = *(const float4*)&ap[k0+lk];
    float4 a1 = *(const float4*)&ap[k0+lk+4];
    float4 w0 = *(const float4*)&wp[k0+lk];
    float4 w1 = *(const float4*)&wp[k0+lk+4];
    __syncthreads();                       // protect previous iteration's reads
    As[lk+0][lr]=a0.x; As[lk+1][lr]=a0.y; As[lk+2][lr]=a0.z; As[lk+3][lr]=a0.w;
    As[lk+4][lr]=a1.x; As[lk+5][lr]=a1.y; As[lk+6][lr]=a1.z; As[lk+7][lr]=a1.w;
    Bs[lk+0][lr]=w0.x; Bs[lk+1][lr]=w0.y; Bs[lk+2][lr]=w0.z; Bs[lk+3][lr]=w0.w;
    Bs[lk+4][lr]=w1.x; Bs[lk+5][lr]=w1.y; Bs[lk+6][lr]=w1.z; Bs[lk+7][lr]=w1.w;
    __syncthreads();
    #pragma unroll
    for (int kk = 0; kk < 32; kk++){
      float4 av = *(const float4*)&As[kk][ty*4];
      float4 bv = *(const float4*)&Bs[kk][tx*4];
      acc[0][0]+=av.x*bv.x; acc[0][1]+=av.x*bv.y; acc[0][2]+=av.x*bv.z; acc[0][3]+=av.x*bv.w;
      acc[1][0]+=av.y*bv.x; acc[1][1]+=av.y*bv.y; acc[1][2]+=av.y*bv.z; acc[1][3]+=av.y*bv.w;
      acc[2][0]+=av.z*bv.x; acc[2][1]+=av.z*bv.y; acc[2][2]+=av.z*bv.z; acc[2][3]+=av.z*bv.w;
      acc[3][0]+=av.w*bv.x; acc[3][1]+=av.w*bv.y; acc[3][2]+=av.w*bv.z; acc[3][3]+=av.w*bv.w;
    }
  }

  const size_t gbase = (size_t)dir*NSEQ*FOURH;
  #pragma unroll
  for (int i = 0; i < 4; i++){
    const int n = n0 + ty*4 + i;
    #pragma unroll
    for (int j = 0; j < 4; j++){
      const int m = m0 + tx*4 + j;
      g[gbase + (size_t)n*FOURH + m] = acc[i][j] + bias[m];
    }
  }
}

// ---------------------------------------------------------------------------
// Sequential bidirectional scan.
// 64 workgroups (32/dir) x 1024 threads. wg owns 16 hidden units (64 z-rows).
// Weights live in VGPRs (wA/wB, 16 each). h sync is value-carried: writers
// atomic-store h (agent scope) + release fence; readers acquire-fence and
// vector-load until no lane sees the 0xAA poison pattern.
// Thread map: wave wv(0..15), lane: s=lane&31 (k-slice of 16), rb=lane>>5.
// rows r0=4*wv+rb, r1=r0+2 (local row r = 16*gate + hid).
// ---------------------------------------------------------------------------
#define DPP_ROR_ADD(v, ctrl) do { \
    int _t = __builtin_amdgcn_update_dpp(0, __float_as_int(v), (ctrl), 0xf, 0xf, false); \
    (v) += __int_as_float(_t); } while (0)

__global__ __launch_bounds__(1024, 4) void scan_k(
    const float* __restrict__ Whh_f, const float* __restrict__ Whh_b,
    const float* __restrict__ c0, const float* __restrict__ g,
    float* __restrict__ hbuf, float* __restrict__ out)
{
  const int bx  = blockIdx.x;
  const int dir = bx >> 5;
  const int w   = bx & 31;
  const int j0  = w << 4;
  const int tid  = threadIdx.x;
  const int lane = tid & 63;
  const int wv   = tid >> 6;
  const int s    = lane & 31;
  const int rb   = lane >> 5;
  const int r0   = (wv << 2) + rb;
  const int r1   = r0 + 2;

  const float* __restrict__ Whh = dir ? Whh_b : Whh_f;

  __shared__ float zbuf[64];
  __shared__ int dead;

  // Preload recurrent weights into VGPRs: rows r0/r1, k-slice [16s, 16s+16)
  float wA[16], wB[16];
  {
    const int gA = r0 >> 4, hA = r0 & 15;
    const int gB = r1 >> 4, hB = r1 & 15;
    const float* pa = &Whh[(size_t)(gA*HH + j0 + hA)*HH + (s<<4)];
    const float* pb = &Whh[(size_t)(gB*HH + j0 + hB)*HH + (s<<4)];
    #pragma unroll
    for (int q = 0; q < 4; q++){
      float4 va = ((const float4*)pa)[q];
      wA[4*q+0]=va.x; wA[4*q+1]=va.y; wA[4*q+2]=va.z; wA[4*q+3]=va.w;
      float4 vb = ((const float4*)pb)[q];
      wB[4*q+0]=vb.x; wB[4*q+1]=vb.y; wB[4*q+2]=vb.z; wB[4*q+3]=vb.w;
    }
  }

  float cst = 0.f;
  if (tid < 16) cst = c0[dir*HH + j0 + tid];
  if (tid == 0) dead = 0;
  __syncthreads();

  float* __restrict__ hb = hbuf + (size_t)dir*(NSEQ+1)*HH;
  const float* __restrict__ gbp = g + (size_t)dir*NSEQ*FOURH;

  for (int t = 0; t < NSEQ; t++){
    // Prefetch this step's input-gate contributions (no h dependency).
    float gvi=0.f, gvf=0.f, gvg=0.f, gvo=0.f;
    if (tid < 16){
      const float* gp = &gbp[(size_t)t*FOURH + j0 + tid];
      gvi = gp[0]; gvf = gp[HH]; gvg = gp[2*HH]; gvo = gp[3*HH];
    }

    // Poll-load h[t] slice (16 floats/lane) until no poison remains.
    const float4* __restrict__ hp = (const float4*)&hb[(size_t)t*HH + (s<<4)];
    float4 h4a, h4b, h4c, h4d;
    {
      int it = 0;
      for (;;){
        __builtin_amdgcn_fence(__ATOMIC_ACQUIRE, "agent");
        h4a = hp[0]; h4b = hp[1]; h4c = hp[2]; h4d = hp[3];
        bool ok = (__float_as_uint(h4a.x)!=POISON) & (__float_as_uint(h4a.y)!=POISON)
                & (__float_as_uint(h4a.z)!=POISON) & (__float_as_uint(h4a.w)!=POISON)
                & (__float_as_uint(h4b.x)!=POISON) & (__float_as_uint(h4b.y)!=POISON)
                & (__float_as_uint(h4b.z)!=POISON) & (__float_as_uint(h4b.w)!=POISON)
                & (__float_as_uint(h4c.x)!=POISON) & (__float_as_uint(h4c.y)!=POISON)
                & (__float_as_uint(h4c.z)!=POISON) & (__float_as_uint(h4c.w)!=POISON)
                & (__float_as_uint(h4d.x)!=POISON) & (__float_as_uint(h4d.y)!=POISON)
                & (__float_as_uint(h4d.z)!=POISON) & (__float_as_uint(h4d.w)!=POISON);
        if (ok) break;
        if (++it > POLL_CAP){ dead = 1; break; }   // fail fast, never hang
        __builtin_amdgcn_s_sleep(2);
      }
    }

    // Two 16-long dot products per lane (4 independent FMA chains).
    float a0=0.f, a1=0.f, b0=0.f, b1=0.f;
    a0 += wA[ 0]*h4a.x; a1 += wA[ 1]*h4a.y; a0 += wA[ 2]*h4a.z; a1 += wA[ 3]*h4a.w;
    a0 += wA[ 4]*h4b.x; a1 += wA[ 5]*h4b.y; a0 += wA[ 6]*h4b.z; a1 += wA[ 7]*h4b.w;
    a0 += wA[ 8]*h4c.x; a1 += wA[ 9]*h4c.y; a0 += wA[10]*h4c.z; a1 += wA[11]*h4c.w;
    a0 += wA[12]*h4d.x; a1 += wA[13]*h4d.y; a0 += wA[14]*h4d.z; a1 += wA[15]*h4d.w;
    b0 += wB[ 0]*h4a.x; b1 += wB[ 1]*h4a.y; b0 += wB[ 2]*h4a.z; b1 += wB[ 3]*h4a.w;
    b0 += wB[ 4]*h4b.x; b1 += wB[ 5]*h4b.y; b0 += wB[ 6]*h4b.z; b1 += wB[ 7]*h4b.w;
    b0 += wB[ 8]*h4c.x; b1 += wB[ 9]*h4c.y; b0 += wB[10]*h4c.z; b1 += wB[11]*h4c.w;
    b0 += wB[12]*h4d.x; b1 += wB[13]*h4d.y; b0 += wB[14]*h4d.z; b1 += wB[15]*h4d.w;
    float accA = a0 + a1, accB = b0 + b1;

    // Reduce across the 32 k-slices: 4 DPP row-rotates (within 16) + one
    // ds_swizzle xor-16 (within the 32-lane half). All lanes end with the sum.
    DPP_ROR_ADD(accA, 0x128); DPP_ROR_ADD(accA, 0x124);
    DPP_ROR_ADD(accA, 0x122); DPP_ROR_ADD(accA, 0x121);
    accA += __int_as_float(__builtin_amdgcn_ds_swizzle(__float_as_int(accA), 0x401F));
    DPP_ROR_ADD(accB, 0x128); DPP_ROR_ADD(accB, 0x124);
    DPP_ROR_ADD(accB, 0x122); DPP_ROR_ADD(accB, 0x121);
    accB += __int_as_float(__builtin_amdgcn_ds_swizzle(__float_as_int(accB), 0x401F));

    if (s == 0){ zbuf[r0] = accA; zbuf[r1] = accB; }
    __syncthreads();
    if (dead) break;

    // Gate math + state update for this wg's 16 hidden units.
    if (tid < 16){
      float zi = zbuf[tid]      + gvi;
      float zf = zbuf[16 + tid] + gvf;
      float zg = zbuf[32 + tid] + gvg;
      float zo = zbuf[48 + tid] + gvo;
      float si = 1.f/(1.f + __expf(-zi));
      float sf = 1.f/(1.f + __expf(-zf));
      float so = 1.f/(1.f + __expf(-zo));
      float e2g = __expf(2.f*zg);
      float tg  = (e2g - 1.f)/(e2g + 1.f);
      cst = sf*cst + si*tg;
      float e2c = __expf(2.f*cst);
      float tc  = (e2c - 1.f)/(e2c + 1.f);
      float hv  = so*tc;
      uint32_t u = __float_as_uint(hv);
      if (u == POISON) hv = __uint_as_float(u ^ 1u);   // keep poison unambiguous

      const int n = dir ? (t ^ 7) : t;                 // undo per-sample reversal
      out[(size_t)n*(2*HH) + dir*HH + j0 + tid] = hv;

      __hip_atomic_store(&hb[(size_t)(t+1)*HH + j0 + tid], hv,
                         __ATOMIC_RELAXED, __HIP_MEMORY_SCOPE_AGENT);
      __builtin_amdgcn_fence(__ATOMIC_RELEASE, "agent"); // flush L2 cross-XCD

      if (t == NSEQ-1){
        out[(size_t)NSEQ*2*HH + dir*HH + j0 + tid] = hv;          // h_n
        out[(size_t)NSEQ*2*HH + 2*HH + dir*HH + j0 + tid] = cst;  // c_n
      }
    }
    // No trailing barrier needed: any wave's next-step zbuf write is gated on
    // h[t+1] being visible, which requires this wg's gate threads to be done.
  }
}

// ---------------------------------------------------------------------------
extern "C" void kernel_launch(void* const* d_in, const int* in_sizes, int n_in,
                              void* d_out, int out_size, void* d_ws, size_t ws_size,
                              hipStream_t stream)
{
  const float* x    = (const float*)d_in[0];
  const float* h0   = (const float*)d_in[1];
  const float* c0   = (const float*)d_in[2];
  const float* Wihf = (const float*)d_in[3];
  const float* Whhf = (const float*)d_in[4];
  const float* bf   = (const float*)d_in[5];
  const float* Wihb = (const float*)d_in[6];
  const float* Whhb = (const float*)d_in[7];
  const float* bb   = (const float*)d_in[8];
  float* out = (float*)d_out;
  float* ws  = (float*)d_ws;

  float* g    = ws;                 // [2][8192][2048] fp32
  float* hbuf = ws + G_ELEMS;       // [2][8193][512]  fp32

  {
    int total = (int)HB_ELEMS;
    int blocks = (total + 255) / 256;
    init_hbuf_k<<<blocks, 256, 0, stream>>>(hbuf, h0);
  }
  {
    dim3 grid(NSEQ/64, (2*FOURH)/64);   // (128, 64)
    gemm_ih_k<<<grid, 256, 0, stream>>>(x, Wihf, bf, Wihb, bb, g);
  }
  scan_k<<<64, 1024, 0, stream>>>(Whhf, Whhb, c0, g, hbuf, out);
}

// Round 2
// 12695.741 us; speedup vs baseline: 8.6171x; 8.6171x over previous
//
#include <hip/hip_runtime.h>
#include <stdint.h>

// Problem dims (fixed by the reference)
#define BSZ   1024
#define TT    8
#define DD    512
#define HH    512
#define NSEQ  (BSZ*TT)          // 8192 sequential steps per direction
#define FOURH (4*HH)            // 2048
#define POISON 0xAAAAAAAAu
#define G_ELEMS  ((size_t)2*NSEQ*FOURH)      // 33,554,432 floats (128 MB)
#define HB_ELEMS ((size_t)2*(NSEQ+1)*HH)     //  8,389,632 floats (32 MB)
#define POLL_CAP (1<<16)

typedef __attribute__((ext_vector_type(4))) float vf4;

// IC-coherent 32B load (bypasses L1+L2; no cache-invalidate side effects).
__device__ __forceinline__ void ld2x16_ic(const float* p, vf4& a, vf4& b){
  asm volatile("global_load_dwordx4 %0, %2, off sc0 sc1\n\t"
               "global_load_dwordx4 %1, %2, off offset:16 sc0 sc1\n\t"
               "s_waitcnt vmcnt(0)"
               : "=v"(a), "=v"(b) : "v"(p) : "memory");
}
// IC-coherent 4B publish store.
__device__ __forceinline__ void st_ic(float* p, float v){
  asm volatile("global_store_dword %0, %1, off sc0 sc1"
               :: "v"(p), "v"(v) : "memory");
}

// ---------------------------------------------------------------------------
// Init: poison the h-pipeline buffer, seed slot 0 with h0 (LSB-flip if it
// happens to equal the poison bit pattern). End-of-dispatch flush makes these
// visible at IC scope for scan_k's bypassing loads.
// ---------------------------------------------------------------------------
__global__ void init_hbuf_k(float* __restrict__ hbuf, const float* __restrict__ h0)
{
  size_t idx = (size_t)blockIdx.x*blockDim.x + threadIdx.x;
  if (idx >= HB_ELEMS) return;
  int j = (int)(idx % HH);
  size_t r = idx / HH;
  int t   = (int)(r % (NSEQ+1));
  int dir = (int)(r / (NSEQ+1));
  uint32_t v;
  if (t == 0){
    uint32_t u = __float_as_uint(h0[dir*HH + j]);
    if (u == POISON) u ^= 1u;
    v = u;
  } else {
    v = POISON;
  }
  ((uint32_t*)hbuf)[idx] = v;
}

// ---------------------------------------------------------------------------
// Input-side GEMM: g[dir][n][m] = x[row]·W_ih_dir[m] + b_dir[m]
//   dir 0: row = n ; dir 1: row = n^7  (per-sample time reversal, T=8)
// ---------------------------------------------------------------------------
__global__ __launch_bounds__(256) void gemm_ih_k(
    const float* __restrict__ x,
    const float* __restrict__ Wf, const float* __restrict__ bf,
    const float* __restrict__ Wb, const float* __restrict__ bb,
    float* __restrict__ g)
{
  const int bm = blockIdx.x;          // 128 row tiles
  const int bn = blockIdx.y;          // 64 col tiles over combined N=4096
  const int n0  = bm*64;
  const int m0g = bn*64;
  const int dir = m0g >> 11;          // /2048
  const int m0  = m0g & 2047;
  const float* __restrict__ W    = dir ? Wb : Wf;
  const float* __restrict__ bias = dir ? bb : bf;

  __shared__ float As[32][68];
  __shared__ float Bs[32][68];

  const int tid = threadIdx.x;
  const int tx = tid & 15, ty = tid >> 4;
  float acc[4][4] = {};

  const int lr = tid >> 2;            // 0..63
  const int lk = (tid & 3) * 8;       // 0,8,16,24
  int arow = n0 + lr; if (dir) arow ^= 7;
  const float* ap = &x[(size_t)arow*DD];
  const float* wp = &W[(size_t)(m0+lr)*DD];

  for (int k0 = 0; k0 < DD; k0 += 32){
    float4 a0 = *(const float4*)&ap[k0+lk];
    float4 a1 = *(const float4*)&ap[k0+lk+4];
    float4 w0 = *(const float4*)&wp[k0+lk];
    float4 w1 = *(const float4*)&wp[k0+lk+4];
    __syncthreads();
    As[lk+0][lr]=a0.x; As[lk+1][lr]=a0.y; As[lk+2][lr]=a0.z; As[lk+3][lr]=a0.w;
    As[lk+4][lr]=a1.x; As[lk+5][lr]=a1.y; As[lk+6][lr]=a1.z; As[lk+7][lr]=a1.w;
    Bs[lk+0][lr]=w0.x; Bs[lk+1][lr]=w0.y; Bs[lk+2][lr]=w0.z; Bs[lk+3][lr]=w0.w;
    Bs[lk+4][lr]=w1.x; Bs[lk+5][lr]=w1.y; Bs[lk+6][lr]=w1.z; Bs[lk+7][lr]=w1.w;
    __syncthreads();
    #pragma unroll
    for (int kk = 0; kk < 32; kk++){
      float4 av = *(const float4*)&As[kk][ty*4];
      float4 bv = *(const float4*)&Bs[kk][tx*4];
      acc[0][0]+=av.x*bv.x; acc[0][1]+=av.x*bv.y; acc[0][2]+=av.x*bv.z; acc[0][3]+=av.x*bv.w;
      acc[1][0]+=av.y*bv.x; acc[1][1]+=av.y*bv.y; acc[1][2]+=av.y*bv.z; acc[1][3]+=av.y*bv.w;
      acc[2][0]+=av.z*bv.x; acc[2][1]+=av.z*bv.y; acc[2][2]+=av.z*bv.z; acc[2][3]+=av.z*bv.w;
      acc[3][0]+=av.w*bv.x; acc[3][1]+=av.w*bv.y; acc[3][2]+=av.w*bv.z; acc[3][3]+=av.w*bv.w;
    }
  }

  const size_t gbase = (size_t)dir*NSEQ*FOURH;
  #pragma unroll
  for (int i = 0; i < 4; i++){
    const int n = n0 + ty*4 + i;
    #pragma unroll
    for (int j = 0; j < 4; j++){
      const int m = m0 + tx*4 + j;
      g[gbase + (size_t)n*FOURH + m] = acc[i][j] + bias[m];
    }
  }
}

// ---------------------------------------------------------------------------
// Sequential bidirectional scan, fence-free value-carried sync.
// 64 wgs (32/dir) x 1024 thr. wg owns 16 hidden units (64 z-rows).
// Wave 0 polls h[t] from IC (sc0 sc1 loads), broadcasts via XOR-swizzled LDS;
// all 16 waves compute; gate threads publish h[t+1] with sc0 sc1 stores.
// ---------------------------------------------------------------------------
#define DPP_ROR_ADD(v, ctrl) do { \
    int _t = __builtin_amdgcn_update_dpp(0, __float_as_int(v), (ctrl), 0xf, 0xf, false); \
    (v) += __int_as_float(_t); } while (0)

__global__ __launch_bounds__(1024, 4) void scan_k(
    const float* __restrict__ Whh_f, const float* __restrict__ Whh_b,
    const float* __restrict__ c0, const float* __restrict__ g,
    float* __restrict__ hbuf, float* __restrict__ out)
{
  const int bx  = blockIdx.x;
  const int dir = bx >> 5;
  const int w   = bx & 31;
  const int j0  = w << 4;
  const int tid  = threadIdx.x;
  const int lane = tid & 63;
  const int wv   = tid >> 6;
  const int s    = lane & 31;
  const int rb   = lane >> 5;
  const int r0   = (wv << 2) + rb;
  const int r1   = r0 + 2;

  const float* __restrict__ Whh = dir ? Whh_b : Whh_f;

  __shared__ vf4  hsh4[128];        // h[t] broadcast, XOR-swizzled chunks
  __shared__ float zbuf[64];
  __shared__ float gsh[64];
  __shared__ int dead;

  // Preload recurrent weights into VGPRs: rows r0/r1, k-slice [16s, 16s+16)
  float wA[16], wB[16];
  {
    const int gA = r0 >> 4, hA = r0 & 15;
    const int gB = r1 >> 4, hB = r1 & 15;
    const float* pa = &Whh[(size_t)(gA*HH + j0 + hA)*HH + (s<<4)];
    const float* pb = &Whh[(size_t)(gB*HH + j0 + hB)*HH + (s<<4)];
    #pragma unroll
    for (int q = 0; q < 4; q++){
      float4 va = ((const float4*)pa)[q];
      wA[4*q+0]=va.x; wA[4*q+1]=va.y; wA[4*q+2]=va.z; wA[4*q+3]=va.w;
      float4 vb = ((const float4*)pb)[q];
      wB[4*q+0]=vb.x; wB[4*q+1]=vb.y; wB[4*q+2]=vb.z; wB[4*q+3]=vb.w;
    }
  }

  float cst = 0.f;
  if (tid < 16) cst = c0[dir*HH + j0 + tid];
  if (tid == 0) dead = 0;
  __syncthreads();

  float* __restrict__ hb = hbuf + (size_t)dir*(NSEQ+1)*HH;
  const float* __restrict__ gbp = g + (size_t)dir*NSEQ*FOURH;

  const bool gloader = (tid >= 64) && (tid < 80);
  const int  gl = tid - 64;

  for (int t = 0; t < NSEQ; t++){
    // g prefetch on wave 1 (off the polling wave's critical path).
    float pgi=0.f, pgf=0.f, pgg=0.f, pgo=0.f;
    if (gloader){
      const float* gp = &gbp[(size_t)t*FOURH + j0 + gl];
      pgi = gp[0]; pgf = gp[HH]; pgg = gp[2*HH]; pgo = gp[3*HH];
    }

    // Wave 0: poll h[t] (8 floats/lane) from IC until no poison remains.
    if (wv == 0){
      const float* hp = &hb[(size_t)t*HH + (lane<<3)];
      vf4 a, b;
      int it = 0;
      for (;;){
        ld2x16_ic(hp, a, b);
        bool ok = (__float_as_uint(a.x)!=POISON) & (__float_as_uint(a.y)!=POISON)
                & (__float_as_uint(a.z)!=POISON) & (__float_as_uint(a.w)!=POISON)
                & (__float_as_uint(b.x)!=POISON) & (__float_as_uint(b.y)!=POISON)
                & (__float_as_uint(b.z)!=POISON) & (__float_as_uint(b.w)!=POISON);
        if (ok) break;
        if (++it > POLL_CAP){ dead = 1; break; }
        __builtin_amdgcn_s_sleep(1);
      }
      // Swizzled LDS broadcast: logical chunk c -> phys c ^ ((c>>3)&3).
      const int c0i = lane << 1;                 // 2L
      const int xo  = (c0i >> 3) & 3;
      hsh4[c0i ^ xo]       = a;
      hsh4[(c0i + 1) ^ xo] = b;
    }
    __syncthreads();
    if (dead) break;

    // Read this lane's k-slice [16s,16s+16) from swizzled LDS.
    vf4 h4a, h4b, h4c, h4d;
    {
      const int cb = s << 2;
      h4a = hsh4[(cb+0) ^ (((cb+0)>>3)&3)];
      h4b = hsh4[(cb+1) ^ (((cb+1)>>3)&3)];
      h4c = hsh4[(cb+2) ^ (((cb+2)>>3)&3)];
      h4d = hsh4[(cb+3) ^ (((cb+3)>>3)&3)];
    }

    // Two 16-long dot products per lane (4 independent FMA chains).
    float a0=0.f, a1=0.f, b0=0.f, b1=0.f;
    a0 += wA[ 0]*h4a.x; a1 += wA[ 1]*h4a.y; a0 += wA[ 2]*h4a.z; a1 += wA[ 3]*h4a.w;
    a0 += wA[ 4]*h4b.x; a1 += wA[ 5]*h4b.y; a0 += wA[ 6]*h4b.z; a1 += wA[ 7]*h4b.w;
    a0 += wA[ 8]*h4c.x; a1 += wA[ 9]*h4c.y; a0 += wA[10]*h4c.z; a1 += wA[11]*h4c.w;
    a0 += wA[12]*h4d.x; a1 += wA[13]*h4d.y; a0 += wA[14]*h4d.z; a1 += wA[15]*h4d.w;
    b0 += wB[ 0]*h4a.x; b1 += wB[ 1]*h4a.y; b0 += wB[ 2]*h4a.z; b1 += wB[ 3]*h4a.w;
    b0 += wB[ 4]*h4b.x; b1 += wB[ 5]*h4b.y; b0 += wB[ 6]*h4b.z; b1 += wB[ 7]*h4b.w;
    b0 += wB[ 8]*h4c.x; b1 += wB[ 9]*h4c.y; b0 += wB[10]*h4c.z; b1 += wB[11]*h4c.w;
    b0 += wB[12]*h4d.x; b1 += wB[13]*h4d.y; b0 += wB[14]*h4d.z; b1 += wB[15]*h4d.w;
    float accA = a0 + a1, accB = b0 + b1;

    // Reduce across 32 k-slices: 4 DPP row-rotates (within 16) + xor-16 swizzle.
    DPP_ROR_ADD(accA, 0x128); DPP_ROR_ADD(accA, 0x124);
    DPP_ROR_ADD(accA, 0x122); DPP_ROR_ADD(accA, 0x121);
    accA += __int_as_float(__builtin_amdgcn_ds_swizzle(__float_as_int(accA), 0x401F));
    DPP_ROR_ADD(accB, 0x128); DPP_ROR_ADD(accB, 0x124);
    DPP_ROR_ADD(accB, 0x122); DPP_ROR_ADD(accB, 0x121);
    accB += __int_as_float(__builtin_amdgcn_ds_swizzle(__float_as_int(accB), 0x401F));

    if (s == 0){ zbuf[r0] = accA; zbuf[r1] = accB; }
    if (gloader){ gsh[gl]=pgi; gsh[16+gl]=pgf; gsh[32+gl]=pgg; gsh[48+gl]=pgo; }
    __syncthreads();

    // Gate math + state update for this wg's 16 hidden units.
    if (tid < 16){
      float zi = zbuf[tid]      + gsh[tid];
      float zf = zbuf[16 + tid] + gsh[16 + tid];
      float zg = zbuf[32 + tid] + gsh[32 + tid];
      float zo = zbuf[48 + tid] + gsh[48 + tid];
      float si = 1.f/(1.f + __expf(-zi));
      float sf = 1.f/(1.f + __expf(-zf));
      float so = 1.f/(1.f + __expf(-zo));
      float e2g = __expf(2.f*zg);
      float tg  = (e2g - 1.f)/(e2g + 1.f);
      cst = sf*cst + si*tg;
      float e2c = __expf(2.f*cst);
      float tc  = (e2c - 1.f)/(e2c + 1.f);
      float hv  = so*tc;
      uint32_t u = __float_as_uint(hv);
      if (u == POISON) hv = __uint_as_float(u ^ 1u);   // keep poison unambiguous

      const int n = dir ? (t ^ 7) : t;                 // undo per-sample reversal
      out[(size_t)n*(2*HH) + dir*HH + j0 + tid] = hv;

      st_ic(&hb[(size_t)(t+1)*HH + j0 + tid], hv);     // publish to IC

      if (t == NSEQ-1){
        out[(size_t)NSEQ*2*HH + dir*HH + j0 + tid] = hv;          // h_n
        out[(size_t)NSEQ*2*HH + 2*HH + dir*HH + j0 + tid] = cst;  // c_n
      }
    }
    // No trailing barrier: next-step hsh4/zbuf writes are gated behind the
    // barrier following wave 0's poll of h[t+1], which requires these gate
    // threads (in wave 0) to have finished publishing.
  }
}

// ---------------------------------------------------------------------------
extern "C" void kernel_launch(void* const* d_in, const int* in_sizes, int n_in,
                              void* d_out, int out_size, void* d_ws, size_t ws_size,
                              hipStream_t stream)
{
  const float* x    = (const float*)d_in[0];
  const float* h0   = (const float*)d_in[1];
  const float* c0   = (const float*)d_in[2];
  const float* Wihf = (const float*)d_in[3];
  const float* Whhf = (const float*)d_in[4];
  const float* bf   = (const float*)d_in[5];
  const float* Wihb = (const float*)d_in[6];
  const float* Whhb = (const float*)d_in[7];
  const float* bb   = (const float*)d_in[8];
  float* out = (float*)d_out;
  float* ws  = (float*)d_ws;

  float* g    = ws;                 // [2][8192][2048] fp32
  float* hbuf = ws + G_ELEMS;       // [2][8193][512]  fp32

  {
    int total = (int)HB_ELEMS;
    int blocks = (total + 255) / 256;
    init_hbuf_k<<<blocks, 256, 0, stream>>>(hbuf, h0);
  }
  {
    dim3 grid(NSEQ/64, (2*FOURH)/64);   // (128, 64)
    gemm_ih_k<<<grid, 256, 0, stream>>>(x, Wihf, bf, Wihb, bb, g);
  }
  scan_k<<<64, 1024, 0, stream>>>(Whhf, Whhb, c0, g, hbuf, out);
}